// Round 1
// baseline (2469.788 us; speedup 1.0000x reference)
//
#include <hip/hip_runtime.h>
#include <hip/hip_cooperative_groups.h>

namespace cg = cooperative_groups;

// PageRank power iteration with device-side early exit.
// Reference semantics: v_{t+1} = alpha * M v_t + (1-alpha)/N, committed while
// !done; done latches when sum|v_{t+1}-v_t| < N*TOL (=1.0f). Random 16M-edge
// graph => err after iter 1 ~0.17 < 1.0, so ~1 committed iteration; we still
// compute err faithfully and gate on it.

static constexpr int   NN       = 1000000;
static constexpr int   NE       = 16000000;
static constexpr float ALPHA    = 0.85f;
static constexpr int   MAX_ITER = 100;
static constexpr float THRESH   = 1.0f;                      // float32(N) * 1e-6
static constexpr float INV_N    = 1.0f / 1000000.0f;
static constexpr float TELEPORT = 0.15f * (1.0f / 1000000.0f);

__global__ __launch_bounds__(256, 4)
void pagerank_coop(const int* __restrict__ eidx32,
                   const long long* __restrict__ eidx64,
                   int* __restrict__ deg,
                   float* __restrict__ vA,
                   float* __restrict__ vB,
                   float* __restrict__ w,
                   float* __restrict__ err,
                   int* __restrict__ flags,
                   float* __restrict__ out)
{
    cg::grid_group grid = cg::this_grid();
    const int tid    = blockIdx.x * blockDim.x + threadIdx.x;
    const int stride = gridDim.x * blockDim.x;

    // ---- init: deg=0, v0=1/N, err[]=0, dtype detect ----
    for (int i = tid; i < NN; i += stride) { deg[i] = 0; vA[i] = INV_N; }
    for (int i = tid; i < MAX_ITER; i += stride) err[i] = 0.0f;
    if (tid == 0) {
        // int64 storage => odd int32 words (high halves, values < 2^20) are all 0.
        // int32 storage => odd words are random in [0,1e6): P(all zero) ~ 1e-1536.
        int nz = 0;
        for (int k = 1; k < 512; k += 2) nz |= eidx32[k];
        flags[0] = (nz == 0) ? 1 : 0;
    }
    grid.sync();
    const int is64 = flags[0];

    // ---- out-degree over cols (= edge_index[1]) ----
    if (is64) {
        const long long* cols = eidx64 + NE;
        for (int e = tid; e < NE; e += stride)
            atomicAdd(&deg[(int)cols[e]], 1);
    } else {
        const int* cols = eidx32 + NE;
        for (int e = tid; e < NE; e += stride)
            atomicAdd(&deg[cols[e]], 1);
    }
    grid.sync();

    float* v  = vA;
    float* nv = vB;
    __shared__ float sred[4];

    for (int iter = 0; iter < MAX_ITER; ++iter) {
        // Phase A: w[c] = alpha*v[c]/deg[c] (deg=0 -> inf, never gathered); nv = teleport
        for (int i = tid; i < NN; i += stride) {
            w[i]  = ALPHA * v[i] / (float)deg[i];
            nv[i] = TELEPORT;
        }
        grid.sync();

        // Phase B: SpMV scatter nv[row] += w[col]
        if (is64) {
            const long long* rows = eidx64;
            const long long* cols = eidx64 + NE;
            for (int e = tid; e < NE; e += stride)
                unsafeAtomicAdd(&nv[(int)rows[e]], w[(int)cols[e]]);
        } else {
            const int* rows = eidx32;
            const int* cols = eidx32 + NE;
            for (int e = tid; e < NE; e += stride)
                unsafeAtomicAdd(&nv[rows[e]], w[cols[e]]);
        }
        grid.sync();

        // Phase C: err = sum |nv - v|  (block reduce -> one atomic per block)
        float pe = 0.0f;
        for (int i = tid; i < NN; i += stride)
            pe += fabsf(nv[i] - v[i]);
        #pragma unroll
        for (int off = 32; off > 0; off >>= 1)
            pe += __shfl_down(pe, off, 64);
        const int lane = threadIdx.x & 63;
        const int wid  = threadIdx.x >> 6;
        if (lane == 0) sred[wid] = pe;
        __syncthreads();
        if (threadIdx.x == 0)
            unsafeAtomicAdd(&err[iter], sred[0] + sred[1] + sred[2] + sred[3]);
        grid.sync();

        const float e = ((volatile float*)err)[iter];
        float* t = v; v = nv; nv = t;   // commit (done was false entering this iter)
        if (e < THRESH) break;          // uniform across grid: same err read by all
    }

    for (int i = tid; i < NN; i += stride) out[i] = v[i];
}

extern "C" void kernel_launch(void* const* d_in, const int* in_sizes, int n_in,
                              void* d_out, int out_size, void* d_ws, size_t ws_size,
                              hipStream_t stream)
{
    (void)n_in; (void)out_size; (void)ws_size;
    const void* eidx = d_in[1];   // d_in[0] = x (only used for N in reference)

    char* ws = (char*)d_ws;
    int*   deg   = (int*)(ws);
    float* vA    = (float*)(ws + (size_t) 4 * 1024 * 1024);
    float* vB    = (float*)(ws + (size_t) 8 * 1024 * 1024);
    float* w     = (float*)(ws + (size_t)12 * 1024 * 1024);
    float* err   = (float*)(ws + (size_t)16 * 1024 * 1024);
    int*   flags = (int*)(ws + (size_t)16 * 1024 * 1024 + 4096);
    float* out   = (float*)d_out;

    const int*       e32 = (const int*)eidx;
    const long long* e64 = (const long long*)eidx;

    const int block = 256;
    int maxBlocksPerCU = 0;
    hipOccupancyMaxActiveBlocksPerMultiprocessor(&maxBlocksPerCU,
        (const void*)pagerank_coop, block, 0);
    if (maxBlocksPerCU < 1) maxBlocksPerCU = 1;
    int grid = maxBlocksPerCU * 256;   // 256 CUs on MI355X
    if (grid > 2048) grid = 2048;

    void* args[] = { (void*)&e32, (void*)&e64, (void*)&deg, (void*)&vA, (void*)&vB,
                     (void*)&w, (void*)&err, (void*)&flags, (void*)&out };
    hipLaunchCooperativeKernel((const void*)pagerank_coop,
                               dim3(grid), dim3(block), args, 0, stream);
}

// Round 2
// 2333.242 us; speedup vs baseline: 1.0585x; 1.0585x over previous
//
#include <hip/hip_runtime.h>
#include <hip/hip_cooperative_groups.h>

namespace cg = cooperative_groups;

// PageRank power iteration, device-side early exit.
// R2 change: SpMV scatter accumulates in int32 fixed-point (scale 2^43) via
// int atomicAdd instead of fp32 unsafeAtomicAdd. R1 counters showed the fp32
// atomic stream cost exactly 16M x 64B fabric writes (1.02 GB), while the int
// degree atomics showed ~no write traffic -> int atomics resolve in L2.

static constexpr int   NN       = 1000000;
static constexpr int   NE       = 16000000;
static constexpr float ALPHA    = 0.85f;
static constexpr int   MAX_ITER = 100;
static constexpr float THRESH   = 1.0f;                      // float32(N) * 1e-6
static constexpr float INV_N    = 1.0f / 1000000.0f;
static constexpr float TELEPORT = 0.15f * (1.0f / 1000000.0f);
static constexpr float SCALE    = 8796093022208.0f;          // 2^43
static constexpr float INVSCALE = 1.0f / 8796093022208.0f;   // 2^-43

__global__ __launch_bounds__(256, 4)
void pagerank_coop(const int* __restrict__ eidx32,
                   const long long* __restrict__ eidx64,
                   int* __restrict__ degbuf,     // int deg -> float rdeg (in place)
                   void* __restrict__ bufA,      // rotates: float v / int32 accum
                   void* __restrict__ bufB,
                   float* __restrict__ w,
                   float* __restrict__ err,
                   int* __restrict__ flags,
                   float* __restrict__ out)
{
    cg::grid_group grid = cg::this_grid();
    const int tid    = blockIdx.x * blockDim.x + threadIdx.x;
    const int stride = gridDim.x * blockDim.x;

    // ---- init: deg=0, v0=1/N, err[]=0, dtype detect ----
    float* v0 = (float*)bufA;
    for (int i = tid; i < NN; i += stride) { degbuf[i] = 0; v0[i] = INV_N; }
    for (int i = tid; i < MAX_ITER; i += stride) err[i] = 0.0f;
    if (tid == 0) {
        // int64 storage => odd int32 words (high halves, values < 2^20) all 0.
        int nz = 0;
        for (int k = 1; k < 512; k += 2) nz |= eidx32[k];
        flags[0] = (nz == 0) ? 1 : 0;
    }
    grid.sync();
    const int is64 = flags[0];

    // ---- out-degree over cols (= edge_index[1]) ----
    if (is64) {
        const long long* cols = eidx64 + NE;
        for (int e = tid; e < NE; e += stride)
            atomicAdd(&degbuf[(int)cols[e]], 1);
    } else {
        const int* cols = eidx32 + NE;
        for (int e = tid; e < NE; e += stride)
            atomicAdd(&degbuf[cols[e]], 1);
    }
    grid.sync();

    // deg -> rdeg = alpha/deg, in place (thread-local i mapping, no sync needed
    // before phase A which uses the same grid-stride mapping)
    float* rdeg = (float*)degbuf;
    for (int i = tid; i < NN; i += stride)
        rdeg[i] = ALPHA / (float)degbuf[i];     // deg==0 -> inf, never gathered

    void* vbuf = bufA;   // committed v (float)
    void* abuf = bufB;   // accumulator (int32 fixed point)
    __shared__ float sred[4];

    for (int iter = 0; iter < MAX_ITER; ++iter) {
        const float* v  = (const float*)vbuf;
        int*         ai = (int*)abuf;

        // Phase A: w[i] = alpha*v[i]/deg[i]; accum = 0
        for (int i = tid; i < NN; i += stride) {
            w[i]  = v[i] * rdeg[i];
            ai[i] = 0;
        }
        grid.sync();

        // Phase B: scatter ai[row] += round(w[col] * 2^43)   (int L2 atomics)
        if (is64) {
            const long long* rows = eidx64;
            const long long* cols = eidx64 + NE;
            for (int e = tid; e < NE; e += stride)
                atomicAdd(&ai[(int)rows[e]], __float2int_rn(w[(int)cols[e]] * SCALE));
        } else {
            const int* rows = eidx32;
            const int* cols = eidx32 + NE;
            for (int e = tid; e < NE; e += stride)
                atomicAdd(&ai[rows[e]], __float2int_rn(w[cols[e]] * SCALE));
        }
        grid.sync();

        // Phase C: convert in place to float new_v, accumulate L1 err
        float* nf = (float*)abuf;
        float pe = 0.0f;
        for (int i = tid; i < NN; i += stride) {
            float x = TELEPORT + (float)ai[i] * INVSCALE;
            pe += fabsf(x - v[i]);
            nf[i] = x;
        }
        #pragma unroll
        for (int off = 32; off > 0; off >>= 1)
            pe += __shfl_down(pe, off, 64);
        const int lane = threadIdx.x & 63;
        const int wid  = threadIdx.x >> 6;
        if (lane == 0) sred[wid] = pe;
        __syncthreads();
        if (threadIdx.x == 0)
            unsafeAtomicAdd(&err[iter], sred[0] + sred[1] + sred[2] + sred[3]);
        grid.sync();

        const float e = ((volatile float*)err)[iter];
        void* t = vbuf; vbuf = abuf; abuf = t;   // commit new_v
        if (e < THRESH) break;                   // uniform across grid
    }

    const float* vf = (const float*)vbuf;
    for (int i = tid; i < NN; i += stride) out[i] = vf[i];
}

extern "C" void kernel_launch(void* const* d_in, const int* in_sizes, int n_in,
                              void* d_out, int out_size, void* d_ws, size_t ws_size,
                              hipStream_t stream)
{
    (void)n_in; (void)out_size; (void)ws_size;
    const void* eidx = d_in[1];   // d_in[0] = x (only used for N in reference)

    char* ws = (char*)d_ws;
    int*   deg   = (int*)(ws);
    void*  bufA  = (void*)(ws + (size_t) 4 * 1024 * 1024);
    void*  bufB  = (void*)(ws + (size_t) 8 * 1024 * 1024);
    float* w     = (float*)(ws + (size_t)12 * 1024 * 1024);
    float* err   = (float*)(ws + (size_t)16 * 1024 * 1024);
    int*   flags = (int*)(ws + (size_t)16 * 1024 * 1024 + 4096);
    float* out   = (float*)d_out;

    const int*       e32 = (const int*)eidx;
    const long long* e64 = (const long long*)eidx;

    const int block = 256;
    int maxBlocksPerCU = 0;
    hipOccupancyMaxActiveBlocksPerMultiprocessor(&maxBlocksPerCU,
        (const void*)pagerank_coop, block, 0);
    if (maxBlocksPerCU < 1) maxBlocksPerCU = 1;
    int grid = maxBlocksPerCU * 256;   // 256 CUs on MI355X
    if (grid > 2048) grid = 2048;

    void* args[] = { (void*)&e32, (void*)&e64, (void*)&deg, (void*)&bufA, (void*)&bufB,
                     (void*)&w, (void*)&err, (void*)&flags, (void*)&out };
    hipLaunchCooperativeKernel((const void*)pagerank_coop,
                               dim3(grid), dim3(block), args, 0, stream);
}

// Round 3
// 2019.789 us; speedup vs baseline: 1.2228x; 1.1552x over previous
//
#include <hip/hip_runtime.h>
#include <hip/hip_cooperative_groups.h>

namespace cg = cooperative_groups;

// PageRank power iteration, device-side early exit.
// R3: all 32M device-scope atomics (deg + scatter) replaced by XCD-local
// L2 atomics into 8 per-XCD replicas (xcc = s_getreg(HW_REG_XCC_ID)),
// workgroup-scope atomicAdd => global_atomic_add with no sc flags =>
// resolves in the local XCD L2. R2 counters showed 32M x 32B = 1.03 GB
// fabric write traffic from device-scope atomics regardless of dtype.
// grid.sync (agent acq_rel: buffer_wbl2 + buffer_inv) provides cross-XCD
// visibility for the replica-reduce passes.

static constexpr int   NN       = 1000000;
static constexpr int   NE       = 16000000;
static constexpr float ALPHA    = 0.85f;
static constexpr int   MAX_ITER = 100;
static constexpr float THRESH   = 1.0f;                      // float32(N) * 1e-6
static constexpr float INV_N    = 1.0f / 1000000.0f;
static constexpr float TELEPORT = 0.15f * (1.0f / 1000000.0f);
static constexpr float SCALE    = 8796093022208.0f;          // 2^43
static constexpr float INVSCALE = 1.0f / 8796093022208.0f;   // 2^-43

template<int R>
__device__ __forceinline__ void rep_add(int* p, int v) {
    if (R > 1)   // unscoped: no sc bits -> RMW in the issuing XCD's L2
        __hip_atomic_fetch_add(p, v, __ATOMIC_RELAXED, __HIP_MEMORY_SCOPE_WORKGROUP);
    else         // device scope (fallback path)
        atomicAdd(p, v);
}

template<int R>
__global__ __launch_bounds__(256, 4)
void pagerank_coop(const int* __restrict__ eidx32,
                   const long long* __restrict__ eidx64,
                   int* __restrict__ rep,        // R x NN int accumulators
                   float* __restrict__ rdeg,
                   float* __restrict__ vA,
                   float* __restrict__ vB,
                   float* __restrict__ w,
                   float* __restrict__ err,
                   int* __restrict__ flags,
                   float* __restrict__ out)
{
    cg::grid_group grid = cg::this_grid();
    const int tid    = blockIdx.x * blockDim.x + threadIdx.x;
    const int stride = gridDim.x * blockDim.x;

    int xcc = 0;
    if (R > 1) {
        unsigned x;
        asm volatile("s_getreg_b32 %0, hwreg(HW_REG_XCC_ID)" : "=s"(x));
        xcc = (int)(x & (unsigned)(R - 1));
    }
    int* __restrict__ myrep = rep + (size_t)xcc * NN;

    // ---- init ----
    for (int i = tid; i < R * NN; i += stride) rep[i] = 0;
    for (int i = tid; i < NN; i += stride) vA[i] = INV_N;
    for (int i = tid; i < MAX_ITER; i += stride) err[i] = 0.0f;
    if (tid == 0) {
        // int64 storage => odd int32 words (values < 2^20) all zero.
        int nz = 0;
        for (int k = 1; k < 512; k += 2) nz |= eidx32[k];
        flags[0] = (nz == 0) ? 1 : 0;
    }
    grid.sync();
    const int is64 = flags[0];

    // ---- out-degree over cols into per-XCD replicas ----
    if (is64) {
        const long long* cols = eidx64 + NE;
        for (int e = tid; e < NE; e += stride)
            rep_add<R>(&myrep[(int)cols[e]], 1);
    } else {
        const int4* cols4 = (const int4*)(eidx32 + NE);
        const int nq = NE / 4;
        for (int q = tid; q < nq; q += stride) {
            int4 c = cols4[q];
            rep_add<R>(&myrep[c.x], 1); rep_add<R>(&myrep[c.y], 1);
            rep_add<R>(&myrep[c.z], 1); rep_add<R>(&myrep[c.w], 1);
        }
    }
    grid.sync();

    // ---- deg reduce -> rdeg, zero rep, and w for iteration 0 (all same-thread i) ----
    for (int i = tid; i < NN; i += stride) {
        int d = 0;
        #pragma unroll
        for (int k = 0; k < R; ++k) { d += rep[(size_t)k * NN + i]; rep[(size_t)k * NN + i] = 0; }
        float rd = ALPHA / (float)d;    // deg==0 -> inf, never gathered
        rdeg[i] = rd;
        w[i] = vA[i] * rd;
    }
    grid.sync();

    float* v  = vA;
    float* nv = vB;
    __shared__ float sred[4];

    for (int iter = 0; iter < MAX_ITER; ++iter) {
        if (iter > 0) {
            for (int i = tid; i < NN; i += stride) w[i] = v[i] * rdeg[i];
            grid.sync();
        }

        // Phase B: scatter myrep[row] += round(w[col] * 2^43) (XCD-local L2 atomics)
        if (is64) {
            const long long* rows = eidx64;
            const long long* cols = eidx64 + NE;
            for (int e = tid; e < NE; e += stride)
                rep_add<R>(&myrep[(int)rows[e]], __float2int_rn(w[(int)cols[e]] * SCALE));
        } else {
            const int4* rows4 = (const int4*)eidx32;
            const int4* cols4 = (const int4*)(eidx32 + NE);
            const int nq = NE / 4;
            for (int q = tid; q < nq; q += stride) {
                int4 r = rows4[q];
                int4 c = cols4[q];
                rep_add<R>(&myrep[r.x], __float2int_rn(w[c.x] * SCALE));
                rep_add<R>(&myrep[r.y], __float2int_rn(w[c.y] * SCALE));
                rep_add<R>(&myrep[r.z], __float2int_rn(w[c.z] * SCALE));
                rep_add<R>(&myrep[r.w], __float2int_rn(w[c.w] * SCALE));
            }
        }
        grid.sync();

        // Phase C: reduce replicas -> new v (and re-zero rep for next iter), L1 err
        float pe = 0.0f;
        for (int i = tid; i < NN; i += stride) {
            int s = 0;
            #pragma unroll
            for (int k = 0; k < R; ++k) { s += rep[(size_t)k * NN + i]; rep[(size_t)k * NN + i] = 0; }
            float x = TELEPORT + (float)s * INVSCALE;
            pe += fabsf(x - v[i]);
            nv[i] = x;
        }
        #pragma unroll
        for (int off = 32; off > 0; off >>= 1)
            pe += __shfl_down(pe, off, 64);
        const int lane = threadIdx.x & 63;
        const int wid  = threadIdx.x >> 6;
        if (lane == 0) sred[wid] = pe;
        __syncthreads();
        if (threadIdx.x == 0)
            unsafeAtomicAdd(&err[iter], sred[0] + sred[1] + sred[2] + sred[3]);
        grid.sync();

        const float e = ((volatile float*)err)[iter];
        float* t = v; v = nv; nv = t;   // commit new_v
        if (e < THRESH) break;          // uniform across grid
    }

    for (int i = tid; i < NN; i += stride) out[i] = v[i];
}

extern "C" void kernel_launch(void* const* d_in, const int* in_sizes, int n_in,
                              void* d_out, int out_size, void* d_ws, size_t ws_size,
                              hipStream_t stream)
{
    (void)n_in; (void)out_size;
    const void* eidx = d_in[1];   // d_in[0] = x (only used for N in reference)

    const size_t MB = 1024 * 1024;
    // Layout: rep[R*4MB] | rdeg 4MB | vA 4MB | vB 4MB | w 4MB | err 4KB | flags
    const size_t need8 = 8 * 4 * MB + 16 * MB + 64 * 1024;
    const int R = (ws_size >= need8) ? 8 : 1;

    char* ws = (char*)d_ws;
    int*   rep   = (int*)(ws);
    float* rdeg  = (float*)(ws + (size_t)R * 4 * MB);
    float* vA    = (float*)(ws + (size_t)R * 4 * MB + 4 * MB);
    float* vB    = (float*)(ws + (size_t)R * 4 * MB + 8 * MB);
    float* w     = (float*)(ws + (size_t)R * 4 * MB + 12 * MB);
    float* err   = (float*)(ws + (size_t)R * 4 * MB + 16 * MB);
    int*   flags = (int*)(ws + (size_t)R * 4 * MB + 16 * MB + 4096);
    float* out   = (float*)d_out;

    const int*       e32 = (const int*)eidx;
    const long long* e64 = (const long long*)eidx;

    const void* fn = (R == 8) ? (const void*)pagerank_coop<8>
                              : (const void*)pagerank_coop<1>;

    const int block = 256;
    int maxBlocksPerCU = 0;
    hipOccupancyMaxActiveBlocksPerMultiprocessor(&maxBlocksPerCU, fn, block, 0);
    if (maxBlocksPerCU < 1) maxBlocksPerCU = 1;
    int grid = maxBlocksPerCU * 256;   // 256 CUs on MI355X
    if (grid > 2048) grid = 2048;

    void* args[] = { (void*)&e32, (void*)&e64, (void*)&rep, (void*)&rdeg, (void*)&vA,
                     (void*)&vB, (void*)&w, (void*)&err, (void*)&flags, (void*)&out };
    hipLaunchCooperativeKernel(fn, dim3(grid), dim3(block), args, 0, stream);
}

// Round 4
// 1833.680 us; speedup vs baseline: 1.3469x; 1.1015x over previous
//
#include <hip/hip_runtime.h>
#include <hip/hip_cooperative_groups.h>

namespace cg = cooperative_groups;

// PageRank, R4: propagation-blocking. R1-R3 showed every global atomic
// (any dtype, any scope) = one ~32B fabric transaction, ceiling ~14 G/s ->
// 32M atomics = ~2.2 ms. This version has ZERO global atomics on the hot
// path: edges are counting-sorted into 2048-node destination buckets
// (P1 hist / P2 scan / P3 scatter, LDS-allocated positions), then SpMV
// accumulates per-bucket in LDS (ds_add, int fixed-point 2^43 as in R2).
// Degree histogram gets the same treatment keyed on col.

static constexpr int   NN       = 1000000;
static constexpr int   NE       = 16000000;
static constexpr float ALPHA    = 0.85f;
static constexpr int   MAX_ITER = 100;
static constexpr float THRESH   = 1.0f;                      // float32(N)*1e-6
static constexpr float INV_N    = 1.0f / 1000000.0f;
static constexpr float TELEPORT = 0.15f * (1.0f / 1000000.0f);
static constexpr float SCALE    = 8796093022208.0f;          // 2^43
static constexpr float INVSCALE = 1.0f / 8796093022208.0f;

static constexpr int NBLK  = 1024;           // fixed grid
static constexpr int CHUNK = NE / NBLK;      // 15625 exactly
static constexpr int BSH   = 11;
static constexpr int BSZ   = 1 << BSH;       // 2048 nodes / bucket
static constexpr int NB    = (NN + BSZ - 1) / BSZ;   // 489
static constexpr int NBA   = 512;            // allocated buckets

template<typename T>
__device__ __forceinline__ T ntload(const T* p) { return __builtin_nontemporal_load(p); }

__global__ __launch_bounds__(256, 4)
void pagerank_part(const int* __restrict__ eidx32,
                   const long long* __restrict__ eidx64,
                   unsigned* __restrict__ prow,        // 16M u32: (r&2047)<<20 | c
                   unsigned short* __restrict__ pcol,  // 16M u16: c&2047, bucketed by c>>11
                   unsigned* __restrict__ gh_r,        // [NBA*NBLK]
                   unsigned* __restrict__ gh_c,        // [NBA*NBLK]
                   unsigned* __restrict__ tot,         // [1024] rows | cols
                   unsigned* __restrict__ base,        // [1024]
                   float* __restrict__ rdeg,
                   float* __restrict__ vA,
                   float* __restrict__ vB,
                   float* __restrict__ w,
                   float* __restrict__ err,
                   int* __restrict__ flags,
                   float* __restrict__ out)
{
    cg::grid_group grid = cg::this_grid();
    const int th  = threadIdx.x;
    const int blk = blockIdx.x;
    const int tid = blk * 256 + th;
    const int stride = NBLK * 256;

    __shared__ unsigned u[2048];
    __shared__ float sred[4];

    // ---------------- init ----------------
    for (int i = tid; i < NN; i += stride) vA[i] = INV_N;
    for (int i = tid; i < MAX_ITER; i += stride) err[i] = 0.0f;
    if (tid == 0) {
        int nz = 0;                       // int64 storage => odd words all zero
        for (int k = 1; k < 512; k += 2) nz |= eidx32[k];
        flags[0] = (nz == 0) ? 1 : 0;
    }
    grid.sync();

    if (flags[0]) {
        // ---- int64 fallback: device-atomic path (R2-style), never expected ----
        int* ai  = (int*)prow;
        int* deg = (int*)pcol;
        for (int i = tid; i < NN; i += stride) { ai[i] = 0; deg[i] = 0; }
        grid.sync();
        const long long* rows = eidx64;
        const long long* cols = eidx64 + NE;
        for (int e = tid; e < NE; e += stride) atomicAdd(&deg[(int)cols[e]], 1);
        grid.sync();
        for (int i = tid; i < NN; i += stride) rdeg[i] = ALPHA / (float)deg[i];
        grid.sync();
        float* v = vA; float* nv = vB;
        for (int iter = 0; iter < MAX_ITER; ++iter) {
            for (int i = tid; i < NN; i += stride) { w[i] = v[i] * rdeg[i]; ai[i] = 0; }
            grid.sync();
            for (int e = tid; e < NE; e += stride)
                atomicAdd(&ai[(int)rows[e]], __float2int_rn(w[(int)cols[e]] * SCALE));
            grid.sync();
            float pe = 0.0f;
            for (int i = tid; i < NN; i += stride) {
                float x = TELEPORT + (float)ai[i] * INVSCALE;
                pe += fabsf(x - v[i]); nv[i] = x;
            }
            #pragma unroll
            for (int off = 32; off > 0; off >>= 1) pe += __shfl_down(pe, off, 64);
            if ((th & 63) == 0) sred[th >> 6] = pe;
            __syncthreads();
            if (th == 0) unsafeAtomicAdd(&err[iter], sred[0]+sred[1]+sred[2]+sred[3]);
            grid.sync();
            const float e = ((volatile float*)err)[iter];
            float* t = v; v = nv; nv = t;
            if (e < THRESH) break;
        }
        for (int i = tid; i < NN; i += stride) out[i] = v[i];
        return;
    }

    const int* rows = eidx32;
    const int* cols = eidx32 + NE;

    // ---------------- P1: per-chunk bucket histograms (rows & cols) ----------------
    for (int i = th; i < 1024; i += 256) u[i] = 0;
    __syncthreads();
    {
        const int s0 = blk * CHUNK, s1 = s0 + CHUNK;
        for (int e = s0 + th; e < s1; e += 256) {
            int r = ntload(rows + e);
            int c = ntload(cols + e);
            atomicAdd(&u[r >> BSH], 1u);
            atomicAdd(&u[NBA + (c >> BSH)], 1u);
        }
    }
    __syncthreads();
    for (int b = th; b < NBA; b += 256) {
        gh_r[b * NBLK + blk] = u[b];
        gh_c[b * NBLK + blk] = u[NBA + b];
    }
    grid.sync();

    // ---------------- P2a: per-bucket exclusive scan over blocks ----------------
    {
        unsigned* gh = (blk < NBA) ? gh_r : gh_c;
        const int b  = blk & (NBA - 1);
        unsigned v0 = gh[b*NBLK + 4*th + 0];
        unsigned v1 = gh[b*NBLK + 4*th + 1];
        unsigned v2 = gh[b*NBLK + 4*th + 2];
        unsigned v3 = gh[b*NBLK + 4*th + 3];
        unsigned s  = v0 + v1 + v2 + v3;
        u[th] = s; __syncthreads();
        for (int off = 1; off < 256; off <<= 1) {
            unsigned x = (th >= off) ? u[th - off] : 0u;
            __syncthreads();
            u[th] += x;
            __syncthreads();
        }
        unsigned excl = u[th] - s;
        gh[b*NBLK + 4*th + 0] = excl;
        gh[b*NBLK + 4*th + 1] = excl + v0;
        gh[b*NBLK + 4*th + 2] = excl + v0 + v1;
        gh[b*NBLK + 4*th + 3] = excl + v0 + v1 + v2;
        if (th == 255) tot[(blk < NBA ? 0 : NBA) + b] = u[255];
    }
    grid.sync();

    // ---------------- P2b: scan bucket totals -> bases ----------------
    if (blk < 2) {
        unsigned* t_ = tot  + blk * NBA;
        unsigned* b_ = base + blk * NBA;
        unsigned v0 = t_[2*th], v1 = t_[2*th + 1];
        unsigned s  = v0 + v1;
        u[th] = s; __syncthreads();
        for (int off = 1; off < 256; off <<= 1) {
            unsigned x = (th >= off) ? u[th - off] : 0u;
            __syncthreads();
            u[th] += x;
            __syncthreads();
        }
        unsigned excl = u[th] - s;
        b_[2*th]     = excl;
        b_[2*th + 1] = excl + v0;
    }
    grid.sync();

    // ---------------- P3: scatter edges into buckets (LDS-allocated) ----------------
    for (int b = th; b < NBA; b += 256) {
        u[b]       = base[b]       + gh_r[b*NBLK + blk];
        u[NBA + b] = base[NBA + b] + gh_c[b*NBLK + blk];
    }
    __syncthreads();
    {
        const int s0 = blk * CHUNK, s1 = s0 + CHUNK;
        for (int e = s0 + th; e < s1; e += 256) {
            int r = ntload(rows + e);
            int c = ntload(cols + e);
            unsigned pr = atomicAdd(&u[r >> BSH], 1u);
            prow[pr] = ((unsigned)(r & (BSZ - 1)) << 20) | (unsigned)c;
            unsigned pc = atomicAdd(&u[NBA + (c >> BSH)], 1u);
            pcol[pc] = (unsigned short)(c & (BSZ - 1));
        }
    }
    grid.sync();

    // ---------------- P4: per-bucket degree histogram -> rdeg, w0 ----------------
    if (blk < NB) {
        for (int i = th; i < BSZ; i += 256) u[i] = 0;
        __syncthreads();
        const unsigned s0 = base[NBA + blk], s1 = s0 + tot[NBA + blk];
        for (unsigned e = s0 + th; e < s1; e += 256)
            atomicAdd(&u[ntload(pcol + e)], 1u);
        __syncthreads();
        const int nb = blk * BSZ;
        for (int j = th; j < BSZ && nb + j < NN; j += 256) {
            float rd = ALPHA / (float)u[j];   // deg==0 -> inf, never gathered
            rdeg[nb + j] = rd;
            w[nb + j]    = INV_N * rd;        // fused iter-0 phase A (v0 uniform)
        }
    }
    grid.sync();

    // ---------------- power iterations ----------------
    float* v = vA; float* nv = vB;
    for (int iter = 0; iter < MAX_ITER; ++iter) {
        if (iter > 0) {
            for (int i = tid; i < NN; i += stride) w[i] = v[i] * rdeg[i];
            grid.sync();
        }
        float pe = 0.0f;
        if (blk < NB) {
            for (int i = th; i < BSZ; i += 256) u[i] = 0;
            __syncthreads();
            const unsigned s0 = base[blk], s1 = s0 + tot[blk];
            for (unsigned e = s0 + th; e < s1; e += 256) {
                unsigned pk = ntload(prow + e);
                float val = w[pk & 0xFFFFFu];
                atomicAdd((int*)&u[pk >> 20], __float2int_rn(val * SCALE));
            }
            __syncthreads();
            const int nb = blk * BSZ;
            for (int j = th; j < BSZ && nb + j < NN; j += 256) {
                float x = TELEPORT + (float)(int)u[j] * INVSCALE;
                pe += fabsf(x - v[nb + j]);
                nv[nb + j] = x;
            }
        }
        #pragma unroll
        for (int off = 32; off > 0; off >>= 1) pe += __shfl_down(pe, off, 64);
        if ((th & 63) == 0) sred[th >> 6] = pe;
        __syncthreads();
        if (th == 0) unsafeAtomicAdd(&err[iter], sred[0]+sred[1]+sred[2]+sred[3]);
        grid.sync();
        const float e = ((volatile float*)err)[iter];
        float* t = v; v = nv; nv = t;
        if (e < THRESH) break;
    }

    for (int i = tid; i < NN; i += stride) out[i] = v[i];
}

// ---- emergency fallback (ws too small / occupancy short): R2-style ----
__global__ __launch_bounds__(256, 4)
void pagerank_atomic(const int* __restrict__ eidx32,
                     const long long* __restrict__ eidx64,
                     int* __restrict__ ai, int* __restrict__ deg,
                     float* __restrict__ rdeg, float* __restrict__ vA,
                     float* __restrict__ vB, float* __restrict__ w,
                     float* __restrict__ err, int* __restrict__ flags,
                     float* __restrict__ out)
{
    cg::grid_group grid = cg::this_grid();
    const int tid = blockIdx.x * blockDim.x + threadIdx.x;
    const int stride = gridDim.x * blockDim.x;
    __shared__ float sred[4];

    for (int i = tid; i < NN; i += stride) { vA[i] = INV_N; deg[i] = 0; }
    for (int i = tid; i < MAX_ITER; i += stride) err[i] = 0.0f;
    if (tid == 0) {
        int nz = 0;
        for (int k = 1; k < 512; k += 2) nz |= eidx32[k];
        flags[0] = (nz == 0) ? 1 : 0;
    }
    grid.sync();
    const int is64 = flags[0];
    if (is64) {
        const long long* cols = eidx64 + NE;
        for (int e = tid; e < NE; e += stride) atomicAdd(&deg[(int)cols[e]], 1);
    } else {
        const int* cols = eidx32 + NE;
        for (int e = tid; e < NE; e += stride) atomicAdd(&deg[cols[e]], 1);
    }
    grid.sync();
    for (int i = tid; i < NN; i += stride) rdeg[i] = ALPHA / (float)deg[i];
    grid.sync();
    float* v = vA; float* nv = vB;
    for (int iter = 0; iter < MAX_ITER; ++iter) {
        for (int i = tid; i < NN; i += stride) { w[i] = v[i] * rdeg[i]; ai[i] = 0; }
        grid.sync();
        if (is64) {
            const long long* rows = eidx64; const long long* cols = eidx64 + NE;
            for (int e = tid; e < NE; e += stride)
                atomicAdd(&ai[(int)rows[e]], __float2int_rn(w[(int)cols[e]] * SCALE));
        } else {
            const int* rows = eidx32; const int* cols = eidx32 + NE;
            for (int e = tid; e < NE; e += stride)
                atomicAdd(&ai[rows[e]], __float2int_rn(w[cols[e]] * SCALE));
        }
        grid.sync();
        float pe = 0.0f;
        for (int i = tid; i < NN; i += stride) {
            float x = TELEPORT + (float)ai[i] * INVSCALE;
            pe += fabsf(x - v[i]); nv[i] = x;
        }
        #pragma unroll
        for (int off = 32; off > 0; off >>= 1) pe += __shfl_down(pe, off, 64);
        if ((threadIdx.x & 63) == 0) sred[threadIdx.x >> 6] = pe;
        __syncthreads();
        if (threadIdx.x == 0) unsafeAtomicAdd(&err[iter], sred[0]+sred[1]+sred[2]+sred[3]);
        grid.sync();
        const float e = ((volatile float*)err)[iter];
        float* t = v; v = nv; nv = t;
        if (e < THRESH) break;
    }
    for (int i = tid; i < NN; i += stride) out[i] = v[i];
}

extern "C" void kernel_launch(void* const* d_in, const int* in_sizes, int n_in,
                              void* d_out, int out_size, void* d_ws, size_t ws_size,
                              hipStream_t stream)
{
    (void)n_in; (void)out_size;
    const int*       e32 = (const int*)d_in[1];
    const long long* e64 = (const long long*)d_in[1];
    float* out = (float*)d_out;
    char* ws = (char*)d_ws;

    // main layout (all offsets 256B-aligned)
    const size_t OFF_PROW = 0;                       // 64,000,000
    const size_t OFF_PCOL = 64000000;                // 32,000,000
    const size_t OFF_GHR  = 96000000;                //  2,097,152
    const size_t OFF_GHC  = 98097152;                //  2,097,152
    const size_t OFF_TOT  = 100194304;               //      4,096
    const size_t OFF_BASE = 100198400;               //      4,096
    const size_t OFF_ERR  = 100202496;               //      4,096
    const size_t OFF_FLG  = 100206592;               //      4,096
    const size_t OFF_RDEG = 100210688;               //  4,000,000
    const size_t OFF_VA   = 104210688;
    const size_t OFF_VB   = 108210688;
    const size_t OFF_W    = 112210688;
    const size_t NEED     = 116210688;

    int occ = 0;
    hipOccupancyMaxActiveBlocksPerMultiprocessor(&occ, (const void*)pagerank_part, 256, 0);

    if (ws_size >= NEED && occ >= 4) {
        unsigned*       prow = (unsigned*)(ws + OFF_PROW);
        unsigned short* pcol = (unsigned short*)(ws + OFF_PCOL);
        unsigned*       ghr  = (unsigned*)(ws + OFF_GHR);
        unsigned*       ghc  = (unsigned*)(ws + OFF_GHC);
        unsigned*       tot  = (unsigned*)(ws + OFF_TOT);
        unsigned*       base = (unsigned*)(ws + OFF_BASE);
        float*          err  = (float*)(ws + OFF_ERR);
        int*            flg  = (int*)(ws + OFF_FLG);
        float*          rdeg = (float*)(ws + OFF_RDEG);
        float*          vA   = (float*)(ws + OFF_VA);
        float*          vB   = (float*)(ws + OFF_VB);
        float*          w    = (float*)(ws + OFF_W);
        void* args[] = { (void*)&e32, (void*)&e64, (void*)&prow, (void*)&pcol,
                         (void*)&ghr, (void*)&ghc, (void*)&tot, (void*)&base,
                         (void*)&rdeg, (void*)&vA, (void*)&vB, (void*)&w,
                         (void*)&err, (void*)&flg, (void*)&out };
        hipLaunchCooperativeKernel((const void*)pagerank_part,
                                   dim3(NBLK), dim3(256), args, 0, stream);
        return;
    }

    // fallback: device-atomic version, flexible grid
    const size_t MB = 1024 * 1024;
    int*   ai    = (int*)(ws);
    int*   deg   = (int*)(ws + 4 * MB);
    float* rdeg  = (float*)(ws + 8 * MB);
    float* vA    = (float*)(ws + 12 * MB);
    float* vB    = (float*)(ws + 16 * MB);
    float* w     = (float*)(ws + 20 * MB);
    float* err   = (float*)(ws + 24 * MB);
    int*   flg   = (int*)(ws + 24 * MB + 4096);
    int occ2 = 0;
    hipOccupancyMaxActiveBlocksPerMultiprocessor(&occ2, (const void*)pagerank_atomic, 256, 0);
    if (occ2 < 1) occ2 = 1;
    int grid = occ2 * 256; if (grid > 2048) grid = 2048;
    void* args[] = { (void*)&e32, (void*)&e64, (void*)&ai, (void*)&deg, (void*)&rdeg,
                     (void*)&vA, (void*)&vB, (void*)&w, (void*)&err, (void*)&flg,
                     (void*)&out };
    hipLaunchCooperativeKernel((const void*)pagerank_atomic,
                               dim3(grid), dim3(256), args, 0, stream);
}

// Round 5
// 1414.235 us; speedup vs baseline: 1.7464x; 1.2966x over previous
//
#include <hip/hip_runtime.h>
#include <hip/hip_cooperative_groups.h>

namespace cg = cooperative_groups;

// PageRank, R5: propagation-blocking with write-amplification fix.
// R4 counters: WRITE_SIZE 895 MB vs ~116 MB ideal -> P3 scatter-append kept
// ~8 MB/XCD of partially-filled lines open (> 4 MB L2) while streaming edge
// reads -> repeated partial writebacks + write-allocate refetches.
// R5: P3 on 256 blocks (4x run length, ~1-2 MB/XCD open lines), gh transposed
// to [chunk][bucket] u16 (P1 stores full lines), nt vector loads for all
// streams, bucket bases padded for 16B-aligned vector reads in P4/SpMV.

static constexpr int   NN       = 1000000;
static constexpr int   NE       = 16000000;
static constexpr float ALPHA    = 0.85f;
static constexpr int   MAX_ITER = 100;
static constexpr float THRESH   = 1.0f;                      // float32(N)*1e-6
static constexpr float INV_N    = 1.0f / 1000000.0f;
static constexpr float TELEPORT = 0.15f * (1.0f / 1000000.0f);
static constexpr float SCALE    = 8796093022208.0f;          // 2^43
static constexpr float INVSCALE = 1.0f / 8796093022208.0f;

static constexpr int NBLK  = 1024;           // fixed grid
static constexpr int CHUNK = NE / NBLK;      // 15625
static constexpr int BSH   = 11;
static constexpr int BSZ   = 1 << BSH;       // 2048 nodes / bucket
static constexpr int NB    = (NN + BSZ - 1) / BSZ;   // 489
static constexpr int NBA   = 512;            // allocated buckets
static constexpr int P3B   = 256;            // P3 scatter blocks

typedef int      vint4  __attribute__((ext_vector_type(4)));
typedef unsigned vuint4 __attribute__((ext_vector_type(4)));

template<typename T>
__device__ __forceinline__ T ntload(const T* p) { return __builtin_nontemporal_load(p); }

__global__ __launch_bounds__(256, 4)
void pagerank_part(const int* __restrict__ eidx32,
                   const long long* __restrict__ eidx64,
                   unsigned* __restrict__ prow,        // bucketed by r>>11: (r&2047)<<20 | c
                   unsigned short* __restrict__ pcol,  // bucketed by c>>11: c&2047
                   unsigned short* __restrict__ gh_r,  // [NBLK*NBA] chunk-major
                   unsigned short* __restrict__ gh_c,
                   unsigned* __restrict__ ghs_r,       // [P3B*NBA] chunk-4p prefix
                   unsigned* __restrict__ ghs_c,
                   unsigned* __restrict__ tot,         // [1024] rows | cols
                   unsigned* __restrict__ base,        // [1024] padded bases
                   float* __restrict__ rdeg,
                   float* __restrict__ vA,
                   float* __restrict__ vB,
                   float* __restrict__ w,
                   float* __restrict__ err,
                   int* __restrict__ flags,
                   float* __restrict__ out)
{
    cg::grid_group grid = cg::this_grid();
    const int th  = threadIdx.x;
    const int blk = blockIdx.x;
    const int tid = blk * 256 + th;
    const int stride = NBLK * 256;

    __shared__ unsigned u[2048];
    __shared__ float sred[4];

    // ---------------- init ----------------
    for (int i = tid; i < MAX_ITER; i += stride) err[i] = 0.0f;
    if (tid == 0) {
        int nz = 0;                       // int64 storage => odd words all zero
        for (int k = 1; k < 512; k += 2) nz |= eidx32[k];
        flags[0] = (nz == 0) ? 1 : 0;
    }
    grid.sync();

    if (flags[0]) {
        // ---- int64 fallback: device-atomic path (R2-style), never expected ----
        int* ai  = (int*)prow;
        int* deg = (int*)pcol;
        for (int i = tid; i < NN; i += stride) { ai[i] = 0; deg[i] = 0; vA[i] = INV_N; }
        grid.sync();
        const long long* rows = eidx64;
        const long long* cols = eidx64 + NE;
        for (int e = tid; e < NE; e += stride) atomicAdd(&deg[(int)cols[e]], 1);
        grid.sync();
        for (int i = tid; i < NN; i += stride) rdeg[i] = ALPHA / (float)deg[i];
        grid.sync();
        float* v = vA; float* nv = vB;
        for (int iter = 0; iter < MAX_ITER; ++iter) {
            for (int i = tid; i < NN; i += stride) { w[i] = v[i] * rdeg[i]; ai[i] = 0; }
            grid.sync();
            for (int e = tid; e < NE; e += stride)
                atomicAdd(&ai[(int)rows[e]], __float2int_rn(w[(int)cols[e]] * SCALE));
            grid.sync();
            float pe = 0.0f;
            for (int i = tid; i < NN; i += stride) {
                float x = TELEPORT + (float)ai[i] * INVSCALE;
                pe += fabsf(x - v[i]); nv[i] = x;
            }
            #pragma unroll
            for (int off = 32; off > 0; off >>= 1) pe += __shfl_down(pe, off, 64);
            if ((th & 63) == 0) sred[th >> 6] = pe;
            __syncthreads();
            if (th == 0) unsafeAtomicAdd(&err[iter], sred[0]+sred[1]+sred[2]+sred[3]);
            grid.sync();
            const float e = ((volatile float*)err)[iter];
            float* t = v; v = nv; nv = t;
            if (e < THRESH) break;
        }
        for (int i = tid; i < NN; i += stride) out[i] = v[i];
        return;
    }

    const int* rows = eidx32;
    const int* cols = eidx32 + NE;

    // ---------------- P1: per-chunk bucket histograms (rows & cols) ----------------
    for (int i = th; i < 1024; i += 256) u[i] = 0;
    __syncthreads();
    {
        const int s0 = (blk * CHUNK) & ~3;
        const int s1 = (blk == NBLK - 1) ? NE : (((blk + 1) * CHUNK) & ~3);
        const vint4* r4 = (const vint4*)(rows + s0);
        const vint4* c4 = (const vint4*)(cols + s0);
        const int nq = (s1 - s0) >> 2;
        for (int q = th; q < nq; q += 256) {
            vint4 r = ntload(r4 + q);
            vint4 c = ntload(c4 + q);
            atomicAdd(&u[r.x >> BSH], 1u); atomicAdd(&u[r.y >> BSH], 1u);
            atomicAdd(&u[r.z >> BSH], 1u); atomicAdd(&u[r.w >> BSH], 1u);
            atomicAdd(&u[NBA + (c.x >> BSH)], 1u); atomicAdd(&u[NBA + (c.y >> BSH)], 1u);
            atomicAdd(&u[NBA + (c.z >> BSH)], 1u); atomicAdd(&u[NBA + (c.w >> BSH)], 1u);
        }
    }
    __syncthreads();
    for (int b = th; b < NBA; b += 256) {       // contiguous full-line stores
        gh_r[blk * NBA + b] = (unsigned short)u[b];
        gh_c[blk * NBA + b] = (unsigned short)u[NBA + b];
    }
    grid.sync();

    // ---------------- P2a: per-bucket exclusive scan over 1024 chunks ----------------
    {
        const int side = (blk < NBA) ? 0 : 1;
        const unsigned short* gh = side ? gh_c : gh_r;
        unsigned* ghs            = side ? ghs_c : ghs_r;
        const int b = blk & (NBA - 1);
        unsigned v0 = gh[(4*th + 0) * NBA + b];
        unsigned v1 = gh[(4*th + 1) * NBA + b];
        unsigned v2 = gh[(4*th + 2) * NBA + b];
        unsigned v3 = gh[(4*th + 3) * NBA + b];
        unsigned s  = v0 + v1 + v2 + v3;
        u[th] = s; __syncthreads();
        for (int off = 1; off < 256; off <<= 1) {
            unsigned x = (th >= off) ? u[th - off] : 0u;
            __syncthreads();
            u[th] += x;
            __syncthreads();
        }
        unsigned excl = u[th] - s;              // prefix before chunk 4*th
        ghs[th * NBA + b] = excl;               // P3 block p == th needs exactly this
        if (th == 255) tot[side * NBA + b] = u[255];
    }
    grid.sync();

    // ---------------- P2b: scan padded bucket totals -> aligned bases ----------------
    if (blk < 2) {
        const unsigned amask = (blk == 0) ? 3u : 7u;   // rows: 4-align, cols: 8-align
        const unsigned* t_ = tot  + blk * NBA;
        unsigned* b_       = base + blk * NBA;
        unsigned v0 = (t_[2*th]     + amask) & ~amask;
        unsigned v1 = (t_[2*th + 1] + amask) & ~amask;
        unsigned s  = v0 + v1;
        u[th] = s; __syncthreads();
        for (int off = 1; off < 256; off <<= 1) {
            unsigned x = (th >= off) ? u[th - off] : 0u;
            __syncthreads();
            u[th] += x;
            __syncthreads();
        }
        unsigned excl = u[th] - s;
        b_[2*th]     = excl;
        b_[2*th + 1] = excl + v0;
    }
    grid.sync();

    // ---------------- P3: scatter edges into buckets, 256 blocks ----------------
    if (blk < P3B) {
        for (int b = th; b < NBA; b += 256) {
            u[b]       = base[b]       + ghs_r[blk * NBA + b];
            u[NBA + b] = base[NBA + b] + ghs_c[blk * NBA + b];
        }
        __syncthreads();
        const int s0 = (blk * 4 * CHUNK) & ~3;
        const int s1 = (blk == P3B - 1) ? NE : (((blk + 1) * 4 * CHUNK) & ~3);
        const vint4* r4 = (const vint4*)(rows + s0);
        const vint4* c4 = (const vint4*)(cols + s0);
        const int nq = (s1 - s0) >> 2;
        for (int q = th; q < nq; q += 256) {
            vint4 r = ntload(r4 + q);
            vint4 c = ntload(c4 + q);
            #pragma unroll
            for (int j = 0; j < 4; ++j) {
                int rr = (j == 0) ? r.x : (j == 1) ? r.y : (j == 2) ? r.z : r.w;
                int cc = (j == 0) ? c.x : (j == 1) ? c.y : (j == 2) ? c.z : c.w;
                unsigned pr = atomicAdd(&u[rr >> BSH], 1u);
                prow[pr] = ((unsigned)(rr & (BSZ - 1)) << 20) | (unsigned)cc;
                unsigned pc = atomicAdd(&u[NBA + (cc >> BSH)], 1u);
                pcol[pc] = (unsigned short)(cc & (BSZ - 1));
            }
        }
    }
    grid.sync();

    // ---------------- P4: per-bucket degree histogram -> rdeg, w0 ----------------
    if (blk < NB) {
        for (int i = th; i < BSZ; i += 256) u[i] = 0;
        __syncthreads();
        const unsigned s0 = base[NBA + blk];
        const unsigned cnt = tot[NBA + blk];
        const vuint4* p8 = (const vuint4*)(pcol + s0);   // 8 u16 keys per load
        const unsigned nq = cnt >> 3;
        for (unsigned q = th; q < nq; q += 256) {
            vuint4 x = ntload(p8 + q);
            atomicAdd(&u[x.x & 0xFFFFu], 1u); atomicAdd(&u[x.x >> 16], 1u);
            atomicAdd(&u[x.y & 0xFFFFu], 1u); atomicAdd(&u[x.y >> 16], 1u);
            atomicAdd(&u[x.z & 0xFFFFu], 1u); atomicAdd(&u[x.z >> 16], 1u);
            atomicAdd(&u[x.w & 0xFFFFu], 1u); atomicAdd(&u[x.w >> 16], 1u);
        }
        if ((unsigned)th < (cnt & 7u))
            atomicAdd(&u[pcol[s0 + (cnt & ~7u) + th]], 1u);
        __syncthreads();
        const int nb = blk * BSZ;
        for (int j = th; j < BSZ && nb + j < NN; j += 256) {
            float rd = ALPHA / (float)u[j];   // deg==0 -> inf, never gathered
            rdeg[nb + j] = rd;
            w[nb + j]    = INV_N * rd;        // fused iter-0 phase A (v0 uniform)
        }
    }
    grid.sync();

    // ---------------- power iterations ----------------
    float* v = vA; float* nv = vB;
    for (int iter = 0; iter < MAX_ITER; ++iter) {
        if (iter > 0) {
            for (int i = tid; i < NN; i += stride) w[i] = v[i] * rdeg[i];
            grid.sync();
        }
        float pe = 0.0f;
        if (blk < NB) {
            for (int i = th; i < BSZ; i += 256) u[i] = 0;
            __syncthreads();
            const unsigned s0 = base[blk];
            const unsigned cnt = tot[blk];
            const vuint4* p4 = (const vuint4*)(prow + s0);
            const unsigned nq = cnt >> 2;
            for (unsigned q = th; q < nq; q += 256) {
                vuint4 pk = ntload(p4 + q);
                atomicAdd((int*)&u[pk.x >> 20], __float2int_rn(w[pk.x & 0xFFFFFu] * SCALE));
                atomicAdd((int*)&u[pk.y >> 20], __float2int_rn(w[pk.y & 0xFFFFFu] * SCALE));
                atomicAdd((int*)&u[pk.z >> 20], __float2int_rn(w[pk.z & 0xFFFFFu] * SCALE));
                atomicAdd((int*)&u[pk.w >> 20], __float2int_rn(w[pk.w & 0xFFFFFu] * SCALE));
            }
            if ((unsigned)th < (cnt & 3u)) {
                unsigned pk = prow[s0 + (cnt & ~3u) + th];
                atomicAdd((int*)&u[pk >> 20], __float2int_rn(w[pk & 0xFFFFFu] * SCALE));
            }
            __syncthreads();
            const int nb = blk * BSZ;
            for (int j = th; j < BSZ && nb + j < NN; j += 256) {
                float x = TELEPORT + (float)(int)u[j] * INVSCALE;
                float vi = (iter == 0) ? INV_N : v[nb + j];
                pe += fabsf(x - vi);
                nv[nb + j] = x;
            }
        }
        #pragma unroll
        for (int off = 32; off > 0; off >>= 1) pe += __shfl_down(pe, off, 64);
        if ((th & 63) == 0) sred[th >> 6] = pe;
        __syncthreads();
        if (th == 0) unsafeAtomicAdd(&err[iter], sred[0]+sred[1]+sred[2]+sred[3]);
        grid.sync();
        const float e = ((volatile float*)err)[iter];
        float* t = v; v = nv; nv = t;
        if (e < THRESH) break;
    }

    for (int i = tid; i < NN; i += stride) out[i] = v[i];
}

// ---- emergency fallback (ws too small / occupancy short): R2-style ----
__global__ __launch_bounds__(256, 4)
void pagerank_atomic(const int* __restrict__ eidx32,
                     const long long* __restrict__ eidx64,
                     int* __restrict__ ai, int* __restrict__ deg,
                     float* __restrict__ rdeg, float* __restrict__ vA,
                     float* __restrict__ vB, float* __restrict__ w,
                     float* __restrict__ err, int* __restrict__ flags,
                     float* __restrict__ out)
{
    cg::grid_group grid = cg::this_grid();
    const int tid = blockIdx.x * blockDim.x + threadIdx.x;
    const int stride = gridDim.x * blockDim.x;
    __shared__ float sred[4];

    for (int i = tid; i < NN; i += stride) { vA[i] = INV_N; deg[i] = 0; }
    for (int i = tid; i < MAX_ITER; i += stride) err[i] = 0.0f;
    if (tid == 0) {
        int nz = 0;
        for (int k = 1; k < 512; k += 2) nz |= eidx32[k];
        flags[0] = (nz == 0) ? 1 : 0;
    }
    grid.sync();
    const int is64 = flags[0];
    if (is64) {
        const long long* cols = eidx64 + NE;
        for (int e = tid; e < NE; e += stride) atomicAdd(&deg[(int)cols[e]], 1);
    } else {
        const int* cols = eidx32 + NE;
        for (int e = tid; e < NE; e += stride) atomicAdd(&deg[cols[e]], 1);
    }
    grid.sync();
    for (int i = tid; i < NN; i += stride) rdeg[i] = ALPHA / (float)deg[i];
    grid.sync();
    float* v = vA; float* nv = vB;
    for (int iter = 0; iter < MAX_ITER; ++iter) {
        for (int i = tid; i < NN; i += stride) { w[i] = v[i] * rdeg[i]; ai[i] = 0; }
        grid.sync();
        if (is64) {
            const long long* rows = eidx64; const long long* cols = eidx64 + NE;
            for (int e = tid; e < NE; e += stride)
                atomicAdd(&ai[(int)rows[e]], __float2int_rn(w[(int)cols[e]] * SCALE));
        } else {
            const int* rows = eidx32; const int* cols = eidx32 + NE;
            for (int e = tid; e < NE; e += stride)
                atomicAdd(&ai[rows[e]], __float2int_rn(w[cols[e]] * SCALE));
        }
        grid.sync();
        float pe = 0.0f;
        for (int i = tid; i < NN; i += stride) {
            float x = TELEPORT + (float)ai[i] * INVSCALE;
            pe += fabsf(x - v[i]); nv[i] = x;
        }
        #pragma unroll
        for (int off = 32; off > 0; off >>= 1) pe += __shfl_down(pe, off, 64);
        if ((threadIdx.x & 63) == 0) sred[threadIdx.x >> 6] = pe;
        __syncthreads();
        if (threadIdx.x == 0) unsafeAtomicAdd(&err[iter], sred[0]+sred[1]+sred[2]+sred[3]);
        grid.sync();
        const float e = ((volatile float*)err)[iter];
        float* t = v; v = nv; nv = t;
        if (e < THRESH) break;
    }
    for (int i = tid; i < NN; i += stride) out[i] = v[i];
}

extern "C" void kernel_launch(void* const* d_in, const int* in_sizes, int n_in,
                              void* d_out, int out_size, void* d_ws, size_t ws_size,
                              hipStream_t stream)
{
    (void)n_in; (void)out_size;
    const int*       e32 = (const int*)d_in[1];
    const long long* e64 = (const long long*)d_in[1];
    float* out = (float*)d_out;
    char* ws = (char*)d_ws;

    // layout (bytes)
    const size_t OFF_PROW = 0;                     // 16,001,536 u32 = 64,006,144
    const size_t OFF_PCOL = 64006144;              // 16,003,584 u16 = 32,007,168
    const size_t OFF_GHR  = 96013312;              // 1024*512 u16  =  1,048,576
    const size_t OFF_GHC  = 97061888;              //                  1,048,576
    const size_t OFF_GSR  = 98110464;              //  256*512 u32  =    524,288
    const size_t OFF_GSC  = 98634752;              //                    524,288
    const size_t OFF_TOT  = 99159040;              //      4,096
    const size_t OFF_BASE = 99163136;              //      4,096
    const size_t OFF_ERR  = 99167232;              //      4,096
    const size_t OFF_FLG  = 99171328;              //      4,096
    const size_t OFF_RDEG = 99175424;              //  4,000,000
    const size_t OFF_VA   = 103175424;
    const size_t OFF_VB   = 107175424;
    const size_t OFF_W    = 111175424;
    const size_t NEED     = 115175424;

    int occ = 0;
    hipOccupancyMaxActiveBlocksPerMultiprocessor(&occ, (const void*)pagerank_part, 256, 0);

    if (ws_size >= NEED && occ >= 4) {
        unsigned*       prow = (unsigned*)(ws + OFF_PROW);
        unsigned short* pcol = (unsigned short*)(ws + OFF_PCOL);
        unsigned short* ghr  = (unsigned short*)(ws + OFF_GHR);
        unsigned short* ghc  = (unsigned short*)(ws + OFF_GHC);
        unsigned*       gsr  = (unsigned*)(ws + OFF_GSR);
        unsigned*       gsc  = (unsigned*)(ws + OFF_GSC);
        unsigned*       tot  = (unsigned*)(ws + OFF_TOT);
        unsigned*       base = (unsigned*)(ws + OFF_BASE);
        float*          err  = (float*)(ws + OFF_ERR);
        int*            flg  = (int*)(ws + OFF_FLG);
        float*          rdeg = (float*)(ws + OFF_RDEG);
        float*          vA   = (float*)(ws + OFF_VA);
        float*          vB   = (float*)(ws + OFF_VB);
        float*          w    = (float*)(ws + OFF_W);
        void* args[] = { (void*)&e32, (void*)&e64, (void*)&prow, (void*)&pcol,
                         (void*)&ghr, (void*)&ghc, (void*)&gsr, (void*)&gsc,
                         (void*)&tot, (void*)&base, (void*)&rdeg, (void*)&vA,
                         (void*)&vB, (void*)&w, (void*)&err, (void*)&flg, (void*)&out };
        hipLaunchCooperativeKernel((const void*)pagerank_part,
                                   dim3(NBLK), dim3(256), args, 0, stream);
        return;
    }

    // fallback: device-atomic version, flexible grid
    const size_t MB = 1024 * 1024;
    int*   ai    = (int*)(ws);
    int*   deg   = (int*)(ws + 4 * MB);
    float* rdeg  = (float*)(ws + 8 * MB);
    float* vA    = (float*)(ws + 12 * MB);
    float* vB    = (float*)(ws + 16 * MB);
    float* w     = (float*)(ws + 20 * MB);
    float* err   = (float*)(ws + 24 * MB);
    int*   flg   = (int*)(ws + 24 * MB + 4096);
    int occ2 = 0;
    hipOccupancyMaxActiveBlocksPerMultiprocessor(&occ2, (const void*)pagerank_atomic, 256, 0);
    if (occ2 < 1) occ2 = 1;
    int grid = occ2 * 256; if (grid > 2048) grid = 2048;
    void* args[] = { (void*)&e32, (void*)&e64, (void*)&ai, (void*)&deg, (void*)&rdeg,
                     (void*)&vA, (void*)&vB, (void*)&w, (void*)&err, (void*)&flg,
                     (void*)&out };
    hipLaunchCooperativeKernel((const void*)pagerank_atomic,
                               dim3(grid), dim3(256), args, 0, stream);
}